// Round 7
// baseline (393.150 us; speedup 1.0000x reference)
//
#include <hip/hip_runtime.h>
#include <hip/hip_fp8.h>
#include <hip/hip_bf16.h>

// Problem constants: M=8192, H=4096 (=K=N), GROUP=128.
#define MDIM 8192
#define HDIM 4096
#define NKT 128  // K tiles of 32

typedef float f32x4 __attribute__((ext_vector_type(4)));
typedef short bf16x8 __attribute__((ext_vector_type(8)));
typedef unsigned short u16x4 __attribute__((ext_vector_type(4)));

__device__ inline void gload_lds16(const void* g, void* l) {
  __builtin_amdgcn_global_load_lds(
      (const __attribute__((address_space(1))) void*)g,
      (__attribute__((address_space(3))) void*)l, 16, 0, 0);
}

__device__ inline unsigned short f2bf(float f) {
  __hip_bfloat16 h = __float2bfloat16(f);
  return *reinterpret_cast<unsigned short*>(&h);
}

// ---------------------------------------------------------------------------
// Kernel 1: y = silu(gate)*up; per-(1,128) fp8 group quant; emit y_dq as bf16.
// ---------------------------------------------------------------------------
__global__ __launch_bounds__(256) void silu_quant_kernel(
    const float* __restrict__ x, unsigned short* __restrict__ yb) {
  const int m = blockIdx.x;
  const int t = threadIdx.x;
  const int g = t >> 3;   // group 0..31
  const int i = t & 7;    // lane-in-group
  const float* xr = x + (size_t)m * (2 * HDIM);

  float v[16];
  float amax = 0.f;
#pragma unroll
  for (int j = 0; j < 4; ++j) {
    const int off = g * 128 + j * 32 + i * 4;
    f32x4 gate = *(const f32x4*)(xr + off);
    f32x4 up = *(const f32x4*)(xr + HDIM + off);
#pragma unroll
    for (int c = 0; c < 4; ++c) {
      float gg = gate[c];
      float s = gg / (1.f + expf(-gg));
      float val = s * up[c];
      v[j * 4 + c] = val;
      amax = fmaxf(amax, fabsf(val));
    }
  }
#pragma unroll
  for (int d = 1; d < 8; d <<= 1) amax = fmaxf(amax, __shfl_xor(amax, d, 64));
  const float scale = fmaxf(amax, 1e-12f) / 448.0f;

#pragma unroll
  for (int j = 0; j < 4; ++j) {
    u16x4 pk;
#pragma unroll
    for (int c = 0; c < 4; ++c) {
      __hip_fp8_e4m3 qv(v[j * 4 + c] / scale);  // RNE onto e4m3fn grid
      pk[c] = f2bf((float)qv * scale);          // dequantized, to bf16
    }
    *(u16x4*)(yb + (size_t)m * HDIM + g * 128 + j * 32 + i * 4) = pk;
  }
}

// ---------------------------------------------------------------------------
// Kernel 2: wt[n][k] = bf16( w_q[k][n] * wscale[k/128][n/128] )  (transposed)
// ---------------------------------------------------------------------------
__global__ __launch_bounds__(256) void wconv_kernel(
    const float* __restrict__ w, const float* __restrict__ wsc,
    unsigned short* __restrict__ wt) {
  __shared__ unsigned short tile[64][66];
  const int t = threadIdx.x;
  const int n0 = (blockIdx.x & 63) * 64;
  const int k0 = (blockIdx.x >> 6) * 64;
  const float ws = wsc[(k0 >> 7) * 32 + (n0 >> 7)];
  {
    const int r = t >> 4;
    const int c4 = (t & 15) << 2;
#pragma unroll
    for (int j = 0; j < 4; ++j) {
      const int kr = r + j * 16;
      f32x4 vv = *(const f32x4*)(w + (size_t)(k0 + kr) * HDIM + n0 + c4);
#pragma unroll
      for (int c = 0; c < 4; ++c) tile[kr][c4 + c] = f2bf(vv[c] * ws);
    }
  }
  __syncthreads();
  {
    const int n = t >> 4;
    const int k4 = (t & 15) << 2;
#pragma unroll
    for (int j = 0; j < 4; ++j) {
      const int nn = n + j * 16;
      u16x4 pk;
#pragma unroll
      for (int c = 0; c < 4; ++c) pk[c] = tile[k4 + c][nn];
      *(u16x4*)(wt + (size_t)(n0 + nn) * HDIM + k0 + k4) = pk;
    }
  }
}

// ---------------------------------------------------------------------------
// Kernel 3: bf16 GEMM, 256x256 tile, BK=32, 8 waves (2Mx4N, 128x64 each).
// QUAD-buffered LDS (4 x 32KB), depth-3 prefetch, counted vmcnt (never 0 in
// main loop):
//   iter kt: STAGE T(kt+3) -> buf[(kt+3)&3]   (4 gload_lds/thread)
//            COMPUTE T(kt) from buf[kt&3]     (12 ds_read_b128, 32 MFMA)
//            vmcnt(8)  -> T(kt+1)'s 4 loads (oldest) landed; 8 newer in flight
//            lgkmcnt(0); barrier -> T(kt+1) readable by all; buf[(kt)&3] free
// Race-free: stage target buf[(kt+3)&3]=buf[(kt-1)&3] was read-complete at the
// end-of-(kt-1) barrier (each wave lgkmcnt(0) before it).
// LDS layout: [256 rows][64 B]; stored 16B-chunk = c ^ ((row>>1)&3)  -- gives
// exactly 2 lanes per 16B-granule on ds_read_b128 (2-way = free, m136) and on
// linear staging writes. Source pre-swizzled (rule 21).
// XCD swizzle: each XCD owns an 8m x 8n sub-grid (32 MB L2 footprint).
// ---------------------------------------------------------------------------
#define SBAR do { __builtin_amdgcn_sched_barrier(0); __builtin_amdgcn_s_barrier(); __builtin_amdgcn_sched_barrier(0); } while (0)
#define VMW(n) asm volatile("s_waitcnt vmcnt(" #n ")" ::: "memory")
#define LGKM0 asm volatile("s_waitcnt lgkmcnt(0)" ::: "memory")

#define STAGE(bi, kt) do {                                                   \
    const __hip_bfloat16* ga = A + aoff + (size_t)(kt) * 32;                 \
    const __hip_bfloat16* gb = B + boff + (size_t)(kt) * 32;                 \
    unsigned char* la = As + (bi) * 16384 + t * 16;                          \
    unsigned char* lb = Bs + (bi) * 16384 + t * 16;                          \
    gload_lds16(ga, la); gload_lds16(ga + (size_t)128 * HDIM, la + 8192);    \
    gload_lds16(gb, lb); gload_lds16(gb + (size_t)128 * HDIM, lb + 8192);    \
    __builtin_amdgcn_sched_barrier(0);                                       \
  } while (0)

#define COMPUTE(bi) do {                                                     \
    const unsigned char* pa = As + (bi) * 16384;                             \
    const unsigned char* pb = Bs + (bi) * 16384;                             \
    _Pragma("unroll") for (int mi = 0; mi < 8; ++mi)                         \
      afr[mi] = *(const bf16x8*)(pa + (wm * 128 + mi * 16 + lrow) * 64 + cRd * 16); \
    _Pragma("unroll") for (int ni = 0; ni < 4; ++ni)                         \
      bfr[ni] = *(const bf16x8*)(pb + (wn * 64 + ni * 16 + lrow) * 64 + cRd * 16);  \
    __builtin_amdgcn_s_setprio(1);                                           \
    _Pragma("unroll") for (int mi = 0; mi < 8; ++mi)                         \
      _Pragma("unroll") for (int ni = 0; ni < 4; ++ni)                       \
        acc[mi][ni] = __builtin_amdgcn_mfma_f32_16x16x32_bf16(               \
            afr[mi], bfr[ni], acc[mi][ni], 0, 0, 0);                         \
    __builtin_amdgcn_s_setprio(0);                                           \
  } while (0)

__global__ __launch_bounds__(512, 2) void gemm_bf16_kernel(
    const __hip_bfloat16* __restrict__ A,   // y_dq [8192][4096]
    const __hip_bfloat16* __restrict__ B,   // w_dq^T [4096][4096] (n-major)
    float* __restrict__ out) {              // [8192][4096]
  __shared__ __align__(16) unsigned char As[4 * 16384];
  __shared__ __align__(16) unsigned char Bs[4 * 16384];

  // XCD-aware swizzle: grid 512 = 32m x 16n tiles; XCD x gets an 8x8 sub-grid.
  const int bid = blockIdx.x;
  const int x = bid & 7, sub = bid >> 3;
  const int mtile = (x >> 1) * 8 + (sub & 7);
  const int ntile = (x & 1) * 8 + (sub >> 3);
  const int m0 = mtile * 256, n0 = ntile * 256;

  const int t = threadIdx.x;
  const int l = t & 63, wid = t >> 6;
  const int wm = wid >> 2, wn = wid & 3;    // 2x4 waves, 128x64 each
  const int lrow = l & 15, lhi = l >> 4;
  const int cRd = lhi ^ ((lrow >> 1) & 3);  // swizzled read chunk

  // staging: thread t covers rows (t>>2) and 128+(t>>2), stored chunk t&3
  const int cSt = (t & 3) ^ ((t >> 3) & 3); // logical chunk held at (t&3)
  const size_t aoff = (size_t)(m0 + (t >> 2)) * HDIM + cSt * 8;
  const size_t boff = (size_t)(n0 + (t >> 2)) * HDIM + cSt * 8;

  f32x4 acc[8][4];
#pragma unroll
  for (int a = 0; a < 8; ++a)
#pragma unroll
    for (int b = 0; b < 4; ++b) acc[a][b] = (f32x4){0.f, 0.f, 0.f, 0.f};
  bf16x8 afr[8], bfr[4];

  // prologue: stage T0,T1,T2 (12 loads); T0 landed before first compute
  STAGE(0, 0); STAGE(1, 1); STAGE(2, 2);
  VMW(8);
  SBAR;

  for (int kt = 0; kt < NKT - 3; ++kt) {
    STAGE((kt + 3) & 3, kt + 3);  // depth-3 prefetch
    COMPUTE(kt & 3);
    VMW(8);                        // T(kt+1) landed; 8 newer loads in flight
    LGKM0;                         // own ds_reads of T(kt) done
    SBAR;                          // all waves: T(kt+1) readable, buf free
  }
  COMPUTE((NKT - 3) & 3); VMW(4); LGKM0; SBAR;  // T(NKT-2) landed
  COMPUTE((NKT - 2) & 3); VMW(0); LGKM0; SBAR;  // T(NKT-1) landed
  COMPUTE((NKT - 1) & 3);

  // epilogue: C row = lhi*4+r (m), col = lrow (n)
#pragma unroll
  for (int mi = 0; mi < 8; ++mi)
#pragma unroll
    for (int r = 0; r < 4; ++r) {
      const int grow = m0 + wm * 128 + mi * 16 + lhi * 4 + r;
      float* orow = out + (size_t)grow * HDIM + n0 + wn * 64 + lrow;
#pragma unroll
      for (int ni = 0; ni < 4; ++ni) orow[ni * 16] = acc[mi][ni][r];
    }
}

// ---------------------------------------------------------------------------
extern "C" void kernel_launch(void* const* d_in, const int* in_sizes, int n_in,
                              void* d_out, int out_size, void* d_ws, size_t ws_size,
                              hipStream_t stream) {
  const float* x = (const float*)d_in[0];    // [8192][8192]
  const float* wq = (const float*)d_in[1];   // [4096][4096]
  const float* wsc = (const float*)d_in[2];  // [32][32]
  float* out = (float*)d_out;                // [8192][4096]

  unsigned short* yb = (unsigned short*)d_ws;                   // 64 MiB bf16 y_dq
  unsigned short* wt = yb + (size_t)MDIM * HDIM;                // 32 MiB bf16 w_dq^T

  silu_quant_kernel<<<MDIM, 256, 0, stream>>>(x, yb);
  wconv_kernel<<<(HDIM / 64) * (HDIM / 64), 256, 0, stream>>>(wq, wsc, wt);
  gemm_bf16_kernel<<<(MDIM / 256) * (HDIM / 256), 512, 0, stream>>>(
      (const __hip_bfloat16*)yb, (const __hip_bfloat16*)wt, out);
}

// Round 8
// 310.532 us; speedup vs baseline: 1.2661x; 1.2661x over previous
//
#include <hip/hip_runtime.h>
#include <hip/hip_fp8.h>
#include <hip/hip_bf16.h>

// Problem constants: M=8192, H=4096 (=K=N), GROUP=128.
#define MDIM 8192
#define HDIM 4096
#define NKT 64  // K tiles of 64

typedef float f32x4 __attribute__((ext_vector_type(4)));
typedef short bf16x8 __attribute__((ext_vector_type(8)));
typedef unsigned short u16x4 __attribute__((ext_vector_type(4)));

__device__ inline void gload_lds16(const void* g, void* l) {
  __builtin_amdgcn_global_load_lds(
      (const __attribute__((address_space(1))) void*)g,
      (__attribute__((address_space(3))) void*)l, 16, 0, 0);
}

__device__ inline unsigned short f2bf(float f) {
  __hip_bfloat16 h = __float2bfloat16(f);
  return *reinterpret_cast<unsigned short*>(&h);
}

// ---------------------------------------------------------------------------
// Kernel 1: y = silu(gate)*up; per-(1,128) fp8 group quant; emit y_dq as bf16.
// ---------------------------------------------------------------------------
__global__ __launch_bounds__(256) void silu_quant_kernel(
    const float* __restrict__ x, unsigned short* __restrict__ yb) {
  const int m = blockIdx.x;
  const int t = threadIdx.x;
  const int g = t >> 3;   // group 0..31
  const int i = t & 7;    // lane-in-group
  const float* xr = x + (size_t)m * (2 * HDIM);

  float v[16];
  float amax = 0.f;
#pragma unroll
  for (int j = 0; j < 4; ++j) {
    const int off = g * 128 + j * 32 + i * 4;
    f32x4 gate = *(const f32x4*)(xr + off);
    f32x4 up = *(const f32x4*)(xr + HDIM + off);
#pragma unroll
    for (int c = 0; c < 4; ++c) {
      float gg = gate[c];
      float s = gg / (1.f + expf(-gg));
      float val = s * up[c];
      v[j * 4 + c] = val;
      amax = fmaxf(amax, fabsf(val));
    }
  }
#pragma unroll
  for (int d = 1; d < 8; d <<= 1) amax = fmaxf(amax, __shfl_xor(amax, d, 64));
  const float scale = fmaxf(amax, 1e-12f) / 448.0f;

#pragma unroll
  for (int j = 0; j < 4; ++j) {
    u16x4 pk;
#pragma unroll
    for (int c = 0; c < 4; ++c) {
      __hip_fp8_e4m3 qv(v[j * 4 + c] / scale);  // RNE onto e4m3fn grid
      pk[c] = f2bf((float)qv * scale);          // dequantized, to bf16
    }
    *(u16x4*)(yb + (size_t)m * HDIM + g * 128 + j * 32 + i * 4) = pk;
  }
}

// ---------------------------------------------------------------------------
// Kernel 2: wt[n][k] = bf16( w_q[k][n] * wscale[k/128][n/128] )  (transposed)
// ---------------------------------------------------------------------------
__global__ __launch_bounds__(256) void wconv_kernel(
    const float* __restrict__ w, const float* __restrict__ wsc,
    unsigned short* __restrict__ wt) {
  __shared__ unsigned short tile[64][66];
  const int t = threadIdx.x;
  const int n0 = (blockIdx.x & 63) * 64;
  const int k0 = (blockIdx.x >> 6) * 64;
  const float ws = wsc[(k0 >> 7) * 32 + (n0 >> 7)];
  {
    const int r = t >> 4;
    const int c4 = (t & 15) << 2;
#pragma unroll
    for (int j = 0; j < 4; ++j) {
      const int kr = r + j * 16;
      f32x4 vv = *(const f32x4*)(w + (size_t)(k0 + kr) * HDIM + n0 + c4);
#pragma unroll
      for (int c = 0; c < 4; ++c) tile[kr][c4 + c] = f2bf(vv[c] * ws);
    }
  }
  __syncthreads();
  {
    const int n = t >> 4;
    const int k4 = (t & 15) << 2;
#pragma unroll
    for (int j = 0; j < 4; ++j) {
      const int nn = n + j * 16;
      u16x4 pk;
#pragma unroll
      for (int c = 0; c < 4; ++c) pk[c] = tile[k4 + c][nn];
      *(u16x4*)(wt + (size_t)(n0 + nn) * HDIM + k0 + k4) = pk;
    }
  }
}

// ---------------------------------------------------------------------------
// Kernel 3: bf16 GEMM, 256x256 tile, BK=64, 8 waves (2Mx4N, 128x64 each).
// 4 phases per K-tile; per-phase {ds_read quadrant subtile, stage 1 half-tile
// (2 gload_lds), MFMA 16}; 2 barriers/iter; counted vmcnt(2) at iter end.
// Quadrant order (0,0)(1,0)(1,1)(0,1): reads 12/8/4/0 b128; afr0,bfr1 persist.
// Staging ledger (half = 128 rows x 64K x 2B = 16KB = 2 gloads/thread):
//   P1: T(j+1).B-lo -> buf n   (n's occupant T(j-1) fully read last iter)
//   P2: T(j+1).A-hi -> buf n
//   P3: T(j+1).B-hi -> buf n;  then lgkm0+barrier (all reads of buf c DONE)
//   P4: T(j+2).A-lo -> buf c   (legal after P3 barrier); vmcnt(2); barrier
// vmcnt(2) waits exactly T(j+1)'s 8 loads, leaves T(j+2).A-lo flying.
// Induction: at entry of iter j, buf c = T(j) landed, flying = T(j+1).A-lo.
// LDS: [256 rows][128B], stored 16B-chunk = chunk ^ (row&7); linear dest +
// pre-swizzled global source + swizzled ds_read (rule 21). Conflict-free
// (verified r6: SQ_LDS_BANK_CONFLICT = 0).
// ---------------------------------------------------------------------------
#define SCHED0 __builtin_amdgcn_sched_barrier(0)
#define SBAR do { SCHED0; __builtin_amdgcn_s_barrier(); SCHED0; } while (0)
#define VMW(n) asm volatile("s_waitcnt vmcnt(" #n ")" ::: "memory")
#define LGKM0 asm volatile("s_waitcnt lgkmcnt(0)" ::: "memory")
#define PRIO1 __builtin_amdgcn_s_setprio(1)
#define PRIO0 __builtin_amdgcn_s_setprio(0)

// half-tile units: 0 = A-lo, 1 = B-lo, 2 = A-hi, 3 = B-hi
#define STAGE_UNIT(bi, kt, u) do {                                          \
    const __hip_bfloat16* gsrc;  unsigned char* ldst;                       \
    if ((u) == 0)      { gsrc = A + (size_t)(m0 + r0) * HDIM;       ldst = As[bi]; }          \
    else if ((u) == 1) { gsrc = B + (size_t)(n0 + r0) * HDIM;       ldst = Bs[bi]; }          \
    else if ((u) == 2) { gsrc = A + (size_t)(m0 + 128 + r0) * HDIM; ldst = As[bi] + 16384; }  \
    else               { gsrc = B + (size_t)(n0 + 128 + r0) * HDIM; ldst = Bs[bi] + 16384; }  \
    gsrc += (size_t)(kt) * 64 + cst * 8;                                    \
    gload_lds16(gsrc, ldst + t * 16);                                       \
    gload_lds16(gsrc + (size_t)64 * HDIM, ldst + 8192 + t * 16);            \
  } while (0)

#define RD_A(c, mh, dst) do { _Pragma("unroll") for (int mi = 0; mi < 4; ++mi) { \
    const int row = wm * 128 + (mh) * 64 + mi * 16 + lrow;                       \
    _Pragma("unroll") for (int kk = 0; kk < 2; ++kk)                             \
      dst[mi][kk] = *(const bf16x8*)(As[c] + row * 128 + (((kk * 4 + lhi) ^ rx) * 16)); \
  } } while (0)

#define RD_B(c, nh, dst) do { _Pragma("unroll") for (int ni = 0; ni < 2; ++ni) { \
    const int row = wn * 64 + (nh) * 32 + ni * 16 + lrow;                        \
    _Pragma("unroll") for (int kk = 0; kk < 2; ++kk)                             \
      dst[ni][kk] = *(const bf16x8*)(Bs[c] + row * 128 + (((kk * 4 + lhi) ^ rx) * 16)); \
  } } while (0)

#define MFMA16(AF, BF, MB, NB) do { _Pragma("unroll") for (int kk = 0; kk < 2; ++kk) \
    _Pragma("unroll") for (int mi = 0; mi < 4; ++mi)                                 \
      _Pragma("unroll") for (int ni = 0; ni < 2; ++ni)                               \
        acc[(MB) + mi][(NB) + ni] = __builtin_amdgcn_mfma_f32_16x16x32_bf16(         \
            AF[mi][kk], BF[ni][kk], acc[(MB) + mi][(NB) + ni], 0, 0, 0);             \
  } while (0)

#define ITER(j, SH123, SH0, VMSTMT) do {                                     \
    const int c_ = (j) & 1, n_ = c_ ^ 1;                                     \
    /* P1: quadrant (0,0) */                                                 \
    RD_A(c_, 0, afr0); RD_B(c_, 0, bfr0);                                    \
    if (SH123) STAGE_UNIT(n_, (j) + 1, 1);                                   \
    SCHED0;                                                                  \
    PRIO1; MFMA16(afr0, bfr0, 0, 0); PRIO0;                                  \
    /* P2: quadrant (1,0) */                                                 \
    RD_A(c_, 1, afr1);                                                       \
    if (SH123) STAGE_UNIT(n_, (j) + 1, 2);                                   \
    SCHED0;                                                                  \
    PRIO1; MFMA16(afr1, bfr0, 4, 0); PRIO0;                                  \
    /* P3: quadrant (1,1) */                                                 \
    RD_B(c_, 1, bfr1);                                                       \
    if (SH123) STAGE_UNIT(n_, (j) + 1, 3);                                   \
    SCHED0;                                                                  \
    PRIO1; MFMA16(afr1, bfr1, 4, 2); PRIO0;                                  \
    LGKM0; SBAR;  /* all reads of buf c_ complete chip-wide */               \
    /* P4: quadrant (0,1) */                                                 \
    if (SH0) STAGE_UNIT(c_, (j) + 2, 0);                                     \
    SCHED0;                                                                  \
    PRIO1; MFMA16(afr0, bfr1, 0, 2); PRIO0;                                  \
    VMSTMT; SBAR;                                                            \
  } while (0)

__global__ __launch_bounds__(512, 1) void gemm_bf16_kernel(
    const __hip_bfloat16* __restrict__ A,   // y_dq [8192][4096]
    const __hip_bfloat16* __restrict__ B,   // w_dq^T [4096][4096] (n-major)
    float* __restrict__ out) {              // [8192][4096]
  __shared__ __align__(16) unsigned char As[2][32768];
  __shared__ __align__(16) unsigned char Bs[2][32768];

  // XCD-aware swizzle: grid 512 = 32m x 16n tiles; XCD x gets an 8x8 sub-grid.
  const int bid = blockIdx.x;
  const int x = bid & 7, sub = bid >> 3;
  const int mtile = (x >> 1) * 8 + (sub & 7);
  const int ntile = (x & 1) * 8 + (sub >> 3);
  const int m0 = mtile * 256, n0 = ntile * 256;

  const int t = threadIdx.x;
  const int l = t & 63, wid = t >> 6;
  const int wm = wid >> 2, wn = wid & 3;    // 2x4 waves, 128x64 each
  const int lrow = l & 15, lhi = l >> 4;
  const int rx = lrow & 7;

  const int r0 = t >> 3;                    // staging row (0..63)
  const int cst = (t & 7) ^ (r0 & 7);       // pre-swizzled source chunk

  f32x4 acc[8][4];
#pragma unroll
  for (int a = 0; a < 8; ++a)
#pragma unroll
    for (int b = 0; b < 4; ++b) acc[a][b] = (f32x4){0.f, 0.f, 0.f, 0.f};
  bf16x8 afr0[4][2], afr1[4][2], bfr0[2][2], bfr1[2][2];

  // prologue: T0 all 4 halves + T1.A-lo; vmcnt(2) -> T0 landed, T1.A-lo flying
  STAGE_UNIT(0, 0, 0); STAGE_UNIT(0, 0, 1); STAGE_UNIT(0, 0, 2); STAGE_UNIT(0, 0, 3);
  STAGE_UNIT(1, 1, 0);
  VMW(2);
  SBAR;

  for (int j = 0; j <= NKT - 3; ++j) ITER(j, 1, 1, VMW(2));
  ITER(NKT - 2, 1, 0, VMW(0));
  ITER(NKT - 1, 0, 0, (void)0);

  // epilogue: C row = lhi*4+r (m), col = lrow (n)
#pragma unroll
  for (int mi = 0; mi < 8; ++mi)
#pragma unroll
    for (int r = 0; r < 4; ++r) {
      const int grow = m0 + wm * 128 + mi * 16 + lhi * 4 + r;
      float* orow = out + (size_t)grow * HDIM + n0 + wn * 64 + lrow;
#pragma unroll
      for (int ni = 0; ni < 4; ++ni) orow[ni * 16] = acc[mi][ni][r];
    }
}

// ---------------------------------------------------------------------------
extern "C" void kernel_launch(void* const* d_in, const int* in_sizes, int n_in,
                              void* d_out, int out_size, void* d_ws, size_t ws_size,
                              hipStream_t stream) {
  const float* x = (const float*)d_in[0];    // [8192][8192]
  const float* wq = (const float*)d_in[1];   // [4096][4096]
  const float* wsc = (const float*)d_in[2];  // [32][32]
  float* out = (float*)d_out;                // [8192][4096]

  unsigned short* yb = (unsigned short*)d_ws;                   // 64 MiB bf16 y_dq
  unsigned short* wt = yb + (size_t)MDIM * HDIM;                // 32 MiB bf16 w_dq^T

  silu_quant_kernel<<<MDIM, 256, 0, stream>>>(x, yb);
  wconv_kernel<<<(HDIM / 64) * (HDIM / 64), 256, 0, stream>>>(wq, wsc, wt);
  gemm_bf16_kernel<<<(MDIM / 256) * (HDIM / 256), 512, 0, stream>>>(
      (const __hip_bfloat16*)yb, (const __hip_bfloat16*)wt, out);
}